// Round 1
// baseline (29.484 us; speedup 1.0000x reference)
//
#include <hip/hip_runtime.h>

#define TILE 256
#define RC2 6.25f   // (2.5*sigma)^2, sigma=1

__device__ __forceinline__ float wave_reduce_sum(float v) {
    #pragma unroll
    for (int off = 32; off > 0; off >>= 1)
        v += __shfl_down(v, off, 64);
    return v;
}

__global__ __launch_bounds__(TILE) void lj_tiles(const float* __restrict__ pos,
                                                 float* __restrict__ partial,
                                                 int N, int nTiles) {
    // map linear block id -> upper-triangular tile (bi <= bj)
    int t = blockIdx.x;
    int bi = 0;
    int rowlen = nTiles;
    while (t >= rowlen) { t -= rowlen; rowlen--; bi++; }
    int bj = bi + t;

    __shared__ float sx[TILE], sy[TILE], sz[TILE];

    const int i = bi * TILE + threadIdx.x;
    float xi, yi, zi;
    if (i < N) {
        xi = pos[3 * i + 0];
        yi = pos[3 * i + 1];
        zi = pos[3 * i + 2];
    } else {
        xi = -1e30f; yi = -1e30f; zi = -1e30f;  // sentinel: all pairs fail cutoff
    }

    const int jbase = bj * TILE;
    {
        int j = jbase + threadIdx.x;
        if (j < N) {
            sx[threadIdx.x] = pos[3 * j + 0];
            sy[threadIdx.x] = pos[3 * j + 1];
            sz[threadIdx.x] = pos[3 * j + 2];
        } else {
            sx[threadIdx.x] = 1e30f; sy[threadIdx.x] = 1e30f; sz[threadIdx.x] = 1e30f;
        }
    }
    __syncthreads();

    float e = 0.0f;
    if (bi == bj) {
        // diagonal tile: need j > i
        #pragma unroll 8
        for (int k = 0; k < TILE; ++k) {
            int jj = jbase + k;
            float dx = xi - sx[k];
            float dy = yi - sy[k];
            float dz = zi - sz[k];
            float r2 = dx * dx + dy * dy + dz * dz;
            bool ok = (jj > i) && (r2 < RC2);
            float inv = ok ? __builtin_amdgcn_rcpf(r2) : 0.0f;
            float sr6 = inv * inv * inv;
            e += sr6 * sr6 - sr6;
        }
    } else {
        // off-diagonal tile: every j > every i, no index test
        #pragma unroll 8
        for (int k = 0; k < TILE; ++k) {
            float dx = xi - sx[k];
            float dy = yi - sy[k];
            float dz = zi - sz[k];
            float r2 = dx * dx + dy * dy + dz * dz;
            bool ok = (r2 < RC2);
            float inv = ok ? __builtin_amdgcn_rcpf(r2) : 0.0f;
            float sr6 = inv * inv * inv;
            e += sr6 * sr6 - sr6;
        }
    }

    // block reduction -> one partial per block (deterministic, no atomics)
    __shared__ float ssum[TILE / 64];
    float w = wave_reduce_sum(e);
    int lane = threadIdx.x & 63;
    int wid  = threadIdx.x >> 6;
    if (lane == 0) ssum[wid] = w;
    __syncthreads();
    if (threadIdx.x == 0) {
        float tot = 0.0f;
        #pragma unroll
        for (int q = 0; q < TILE / 64; ++q) tot += ssum[q];
        partial[blockIdx.x] = tot * 4.0f;  // 4*EPSILON*(sr12 - sr6)
    }
}

__global__ __launch_bounds__(256) void lj_reduce(const float* __restrict__ partial,
                                                 int n, float* __restrict__ out) {
    float v = 0.0f;
    for (int idx = threadIdx.x; idx < n; idx += 256) v += partial[idx];
    float w = wave_reduce_sum(v);
    __shared__ float ssum[4];
    int lane = threadIdx.x & 63;
    int wid  = threadIdx.x >> 6;
    if (lane == 0) ssum[wid] = w;
    __syncthreads();
    if (threadIdx.x == 0) {
        out[0] = ssum[0] + ssum[1] + ssum[2] + ssum[3];
    }
}

extern "C" void kernel_launch(void* const* d_in, const int* in_sizes, int n_in,
                              void* d_out, int out_size, void* d_ws, size_t ws_size,
                              hipStream_t stream) {
    const float* pos = (const float*)d_in[0];
    float* out = (float*)d_out;
    float* partial = (float*)d_ws;

    int N = in_sizes[0] / 3;
    int nTiles = (N + TILE - 1) / TILE;
    int nBlocks = nTiles * (nTiles + 1) / 2;

    lj_tiles<<<nBlocks, TILE, 0, stream>>>(pos, partial, N, nTiles);
    lj_reduce<<<1, 256, 0, stream>>>(partial, nBlocks, out);
}